// Round 7
// baseline (314.745 us; speedup 1.0000x reference)
//
#include <hip/hip_runtime.h>
#include <hip/hip_fp16.h>

#define RAD 40
#define SEGF 16          // output rows per wave-strip
#define TX 128           // output cols per tile
#define HH 1024
#define WW 1024
#define NSTRIP 64        // HH/SEGF
#define NXT 8            // WW/TX
// scan domain per tile: [x0-RAD, x0+TX+RAD) = 208 cols, padded to 256.
// lane l owns cols 4l..4l+3 (lanes 0..51 carry data) -> SINGLE DPP wave-scan
// per field per row (no chunk chaining, no shfl broadcast).
// History (what's proven):
//  - launch_bounds min-waves >= 4 forced VGPR=40 + ~0.5 GB scratch spills
//    (rounds 1-4); (.,3) restores VGPR>=64 and architectural WRITE=48MB (r5).
//  - DPP wave64 scan beats ds_bpermute shfl scan: K_A 147->133 us (r6).
//  - field-split across 2 waves duplicates issue for no win (r5).
//  - explicit XCD remap scatters per-XCD working sets; natural order wins (r1).
// This round: TX=128 (6144 blocks = 6 waves/SIMD, 2x round-6) with the
// proven-safe register regime.

template<int CTRL, int RMASK>
__device__ __forceinline__ float dpp_add(float v) {
    int t = __builtin_amdgcn_update_dpp(0, __float_as_int(v), CTRL, RMASK, 0xf, false);
    return v + __int_as_float(t);
}

__device__ __forceinline__ float wscan64(float v) {
    v = dpp_add<0x111, 0xf>(v);   // row_shr:1  — intra-16 scan
    v = dpp_add<0x112, 0xf>(v);   // row_shr:2
    v = dpp_add<0x114, 0xf>(v);   // row_shr:4
    v = dpp_add<0x118, 0xf>(v);   // row_shr:8
    v = dpp_add<0x142, 0xa>(v);   // row_bcast:15 -> rows 1,3
    v = dpp_add<0x143, 0xc>(v);   // row_bcast:31 -> rows 2,3
    return v;
}

// ---------------------------------------------------------------------------
// K_A: one wave per (channel, x-tile, y-strip). Vertical sliding sums of
// I, p, I*p, I*I in registers; per-row single DPP scan; writes a,b fp16x2.
// ---------------------------------------------------------------------------
__global__ __launch_bounds__(64, 3)
void fused_ab_kernel(const float* __restrict__ I, const float* __restrict__ p,
                     unsigned int* __restrict__ ab) {
    __shared__ __align__(16) float PF[4][256];
    const int l = threadIdx.x;
    const int bid = (int)blockIdx.x;          // natural dispatch order
    const int strip = bid & (NSTRIP - 1);
    const int xt = (bid >> 6) & (NXT - 1);
    const int c = bid >> 9;
    const int x0 = xt * TX;
    const int y0 = strip * SEGF;
    const size_t plane = (size_t)c * (HH * WW);
    const float* Ib = I + plane;
    const float* pb = p + plane;

    const int g1 = x0 - RAD + 4 * l;     // domain col (mult of 4)
    const bool v1 = (l < 52) && (g1 >= 0) && (g1 < WW);

    // vertical sliding sums [field][k]: 0=I 1=p 2=Ip 3=II
    float s[4][4];
    #pragma unroll
    for (int f = 0; f < 4; ++f)
        #pragma unroll
        for (int k = 0; k < 4; ++k) s[f][k] = 0.f;

    auto ld = [&](const float* base, int y) -> float4 {
        return v1 ? *(const float4*)(base + (size_t)y * WW + g1)
                  : make_float4(0.f, 0.f, 0.f, 0.f);
    };
    auto acc = [&](float4 a, float4 b, float sg) {
        const float* ri = (const float*)&a;
        const float* rp = (const float*)&b;
        #pragma unroll
        for (int k = 0; k < 4; ++k) {
            s[0][k] += sg * ri[k];
            s[1][k] += sg * rp[k];
            s[2][k] += sg * ri[k] * rp[k];
            s[3][k] += sg * ri[k] * ri[k];
        }
    };

    // prime rows [y0-RAD, y0+RAD), row at a time (keeps registers low)
    int yp0 = y0 - RAD; if (yp0 < 0) yp0 = 0;
    int yp1 = y0 + RAD; if (yp1 > HH) yp1 = HH;
    for (int y = yp0; y < yp1; ++y) {
        float4 a0 = ld(Ib, y), b0 = ld(pb, y);
        acc(a0, b0, 1.f);
    }

    float4 pi = make_float4(0.f,0.f,0.f,0.f), pq = pi;
    if (y0 + RAD < HH) { pi = ld(Ib, y0 + RAD); pq = ld(pb, y0 + RAD); }

    for (int yy = y0; yy < y0 + SEGF; ++yy) {
        if (yy + RAD < HH) acc(pi, pq, 1.f);
        // prefetch next add-row and this row's sub-row (hide under scan)
        float4 ni = make_float4(0.f,0.f,0.f,0.f), nq = ni, si = ni, sq = ni;
        const int yn = yy + 1 + RAD;
        const bool nh = (yn < HH) && (yy + 1 < y0 + SEGF);
        if (nh) { ni = ld(Ib, yn); nq = ld(pb, yn); }
        const int ys = yy - RAD;
        if (ys >= 0) { si = ld(Ib, ys); sq = ld(pb, ys); }

        // single DPP scan per field, inclusive prefix -> LDS
        float incl0[4][4];
        #pragma unroll
        for (int f = 0; f < 4; ++f) {
            float c0 = s[f][0];
            float c1 = c0 + s[f][1];
            float c2 = c1 + s[f][2];
            float c3 = c2 + s[f][3];
            float t = wscan64(c3);
            float b0 = t - c3;
            incl0[f][0] = b0 + c0; incl0[f][1] = b0 + c1;
            incl0[f][2] = b0 + c2; incl0[f][3] = b0 + c3;
            ((float4*)PF[f])[l] = make_float4(incl0[f][0], incl0[f][1],
                                              incl0[f][2], incl0[f][3]);
        }
        __syncthreads();   // single-wave workgroup: compiler fence, ~free

        int cv_hi = yy + RAD + 1; if (cv_hi > HH) cv_hi = HH;
        int cv_lo = yy - RAD;     if (cv_lo < 0)  cv_lo = 0;
        const float cntV = (float)(cv_hi - cv_lo);

        if (l < 32) {   // 32 lanes cover the 128 output cols
            float4 hi0 = ((const float4*)PF[0])[l + 20];
            float4 hi1 = ((const float4*)PF[1])[l + 20];
            float4 hi2 = ((const float4*)PF[2])[l + 20];
            float4 hi3 = ((const float4*)PF[3])[l + 20];
            const float* h0 = (const float*)&hi0;
            const float* h1 = (const float*)&hi1;
            const float* h2 = (const float*)&hi2;
            const float* h3 = (const float*)&hi3;

            unsigned int outw[4];
            #pragma unroll
            for (int k = 0; k < 4; ++k) {
                const int go = x0 + 4 * l + k;
                float bI  = h0[k] - (incl0[0][k] - s[0][k]);
                float bp  = h1[k] - (incl0[1][k] - s[1][k]);
                float bIp = h2[k] - (incl0[2][k] - s[2][k]);
                float bII = h3[k] - (incl0[3][k] - s[3][k]);
                int hlo = go - RAD;     if (hlo < 0)  hlo = 0;
                int hhi = go + RAD + 1; if (hhi > WW) hhi = WW;
                const float ic = 1.f / (cntV * (float)(hhi - hlo));
                float mI = bI*ic, mp = bp*ic, mIp = bIp*ic, mII = bII*ic;
                float cov = mIp - mI * mp;
                float var = mII - mI * mI;
                float aa = cov / (var + 1e-3f);
                float bbv = mp - aa * mI;
                __half2 h = __float22half2_rn(make_float2(aa, bbv));
                outw[k] = *reinterpret_cast<unsigned int*>(&h);
            }
            ((uint4*)(ab + plane + (size_t)yy * WW))[(x0 >> 2) + l] =
                make_uint4(outw[0], outw[1], outw[2], outw[3]);
        }

        if (ys >= 0) acc(si, sq, -1.f);
        if (nh) { pi = ni; pq = nq; }
        __syncthreads();   // protect next iter's PF writes vs this iter's reads
    }
}

// ---------------------------------------------------------------------------
// K_B: same structure on packed a,b; epilogue out = mean_a * I + mean_b
// ---------------------------------------------------------------------------
__global__ __launch_bounds__(64, 3)
void fused_out_kernel(const unsigned int* __restrict__ ab, const float* __restrict__ I,
                      float* __restrict__ out) {
    __shared__ __align__(16) float PF[2][256];
    const int l = threadIdx.x;
    const int bid = (int)blockIdx.x;          // natural dispatch order
    const int strip = bid & (NSTRIP - 1);
    const int xt = (bid >> 6) & (NXT - 1);
    const int c = bid >> 9;
    const int x0 = xt * TX;
    const int y0 = strip * SEGF;
    const size_t plane = (size_t)c * (HH * WW);
    const unsigned int* abp = ab + plane;

    const int g1 = x0 - RAD + 4 * l;
    const bool v1 = (l < 52) && (g1 >= 0) && (g1 < WW);

    float s[2][4];
    #pragma unroll
    for (int f = 0; f < 2; ++f)
        #pragma unroll
        for (int k = 0; k < 4; ++k) s[f][k] = 0.f;

    auto ld2 = [&](int y, float* ra, float* rb) {
        uint4 A = v1 ? *(const uint4*)(abp + (size_t)y * WW + g1)
                     : make_uint4(0u, 0u, 0u, 0u);
        const unsigned int* aw = (const unsigned int*)&A;
        #pragma unroll
        for (int k = 0; k < 4; ++k) {
            float2 f2 = __half22float2(*reinterpret_cast<const __half2*>(&aw[k]));
            ra[k] = f2.x; rb[k] = f2.y;
        }
    };
    auto acc2 = [&](const float* ra, const float* rb, float sg) {
        #pragma unroll
        for (int k = 0; k < 4; ++k) {
            s[0][k] += sg * ra[k];
            s[1][k] += sg * rb[k];
        }
    };

    int yp0 = y0 - RAD; if (yp0 < 0) yp0 = 0;
    int yp1 = y0 + RAD; if (yp1 > HH) yp1 = HH;
    for (int y = yp0; y < yp1; ++y) {
        float ra[4], rb[4];
        ld2(y, ra, rb);
        acc2(ra, rb, 1.f);
    }

    float pa[4] = {0.f,0.f,0.f,0.f}, pbv[4] = {0.f,0.f,0.f,0.f};
    if (y0 + RAD < HH) ld2(y0 + RAD, pa, pbv);

    for (int yy = y0; yy < y0 + SEGF; ++yy) {
        if (yy + RAD < HH) acc2(pa, pbv, 1.f);
        float na[4] = {0.f,0.f,0.f,0.f}, nb[4] = {0.f,0.f,0.f,0.f};
        float sa[4] = {0.f,0.f,0.f,0.f}, sb[4] = {0.f,0.f,0.f,0.f};
        const int yn = yy + 1 + RAD;
        const bool nh = (yn < HH) && (yy + 1 < y0 + SEGF);
        if (nh) ld2(yn, na, nb);
        const int ys = yy - RAD;
        if (ys >= 0) ld2(ys, sa, sb);

        float incl0[2][4];
        #pragma unroll
        for (int f = 0; f < 2; ++f) {
            float c0 = s[f][0];
            float c1 = c0 + s[f][1];
            float c2 = c1 + s[f][2];
            float c3 = c2 + s[f][3];
            float t = wscan64(c3);
            float b0 = t - c3;
            incl0[f][0] = b0 + c0; incl0[f][1] = b0 + c1;
            incl0[f][2] = b0 + c2; incl0[f][3] = b0 + c3;
            ((float4*)PF[f])[l] = make_float4(incl0[f][0], incl0[f][1],
                                              incl0[f][2], incl0[f][3]);
        }
        __syncthreads();

        int cv_hi = yy + RAD + 1; if (cv_hi > HH) cv_hi = HH;
        int cv_lo = yy - RAD;     if (cv_lo < 0)  cv_lo = 0;
        const float cntV = (float)(cv_hi - cv_lo);

        if (l < 32) {
            float4 hiA = ((const float4*)PF[0])[l + 20];
            float4 hiB = ((const float4*)PF[1])[l + 20];
            const float* hA = (const float*)&hiA;
            const float* hB = (const float*)&hiB;
            float4 Iv = ((const float4*)(I + plane + (size_t)yy * WW))[(x0 >> 2) + l];
            const float* Ik = (const float*)&Iv;

            float oo[4];
            #pragma unroll
            for (int k = 0; k < 4; ++k) {
                const int go = x0 + 4 * l + k;
                float ba = hA[k] - (incl0[0][k] - s[0][k]);
                float bb = hB[k] - (incl0[1][k] - s[1][k]);
                int hlo = go - RAD;     if (hlo < 0)  hlo = 0;
                int hhi = go + RAD + 1; if (hhi > WW) hhi = WW;
                const float ic = 1.f / (cntV * (float)(hhi - hlo));
                oo[k] = (ba * ic) * Ik[k] + bb * ic;
            }
            ((float4*)(out + plane + (size_t)yy * WW))[(x0 >> 2) + l] =
                make_float4(oo[0], oo[1], oo[2], oo[3]);
        }

        if (ys >= 0) acc2(sa, sb, -1.f);
        if (nh) {
            #pragma unroll
            for (int k = 0; k < 4; ++k) { pa[k] = na[k]; pbv[k] = nb[k]; }
        }
        __syncthreads();
    }
}

extern "C" void kernel_launch(void* const* d_in, const int* in_sizes, int n_in,
                              void* d_out, int out_size, void* d_ws, size_t ws_size,
                              hipStream_t stream) {
    const float* I = (const float*)d_in[0];
    const float* p = (const float*)d_in[1];
    float* out = (float*)d_out;

    const int N = in_sizes[0];           // B*C*H*W
    const int BC = N / (HH * WW);

    unsigned int* ab = (unsigned int*)d_ws;   // fp16x2 {a,b} per pixel

    const int nblk = BC * NXT * NSTRIP;  // BC * 8 * 64 = 6144
    fused_ab_kernel<<<dim3(nblk), 64, 0, stream>>>(I, p, ab);
    fused_out_kernel<<<dim3(nblk), 64, 0, stream>>>(ab, I, out);
}

// Round 8
// 306.932 us; speedup vs baseline: 1.0255x; 1.0255x over previous
//
#include <hip/hip_runtime.h>
#include <hip/hip_fp16.h>

#define RAD 40
#define SEGF 32          // output rows per wave-strip (r8: 16->32, cuts vert amp 6x->3.5x)
#define TX 256           // output cols per tile
#define HH 1024
#define WW 1024
#define NSTRIP 32        // HH/SEGF
// Round-6 champion structure (TX=256, DPP scan, (64,3) bounds) with SEGF=32.
// Rationale (r7 post-mortem): resident waves pin at ~10-11/CU regardless of
// grid size (3072 vs 6144 waves -> 30% vs 35% occ, no speedup), so the kernel
// runs traffic-proportional at ~2.9 TB/s. K_A fetch = 335 MB vs 67 MB ideal
// (6x vertical amp: 96 input rows per 16 output rows). SEGF=32 -> 3.5x amp
// and 2x prime amortization. nblk 3072->1536 (6 blocks/CU, all resident).
// History (proven):
//  - launch_bounds min-waves >= 4 => VGPR=40 + 0.5 GB scratch spills (r1-4);
//    (.,3) restores VGPR>=56 and architectural WRITE=48MB (r5,r7).
//  - DPP wave64 scan beats shfl scan: K_A 147->133 us (r6).
//  - TX=128 costs +13% (idle lanes) at equal traffic (r7); field-split (r5)
//    and XCD remap (r1) both regress. Natural block order.

template<int CTRL, int RMASK>
__device__ __forceinline__ float dpp_add(float v) {
    int t = __builtin_amdgcn_update_dpp(0, __float_as_int(v), CTRL, RMASK, 0xf, false);
    return v + __int_as_float(t);
}

__device__ __forceinline__ float wscan64(float v) {
    v = dpp_add<0x111, 0xf>(v);   // row_shr:1  — intra-16 scan
    v = dpp_add<0x112, 0xf>(v);   // row_shr:2
    v = dpp_add<0x114, 0xf>(v);   // row_shr:4
    v = dpp_add<0x118, 0xf>(v);   // row_shr:8
    v = dpp_add<0x142, 0xa>(v);   // row_bcast:15 -> rows 1,3
    v = dpp_add<0x143, 0xc>(v);   // row_bcast:31 -> rows 2,3
    return v;
}

// ---------------------------------------------------------------------------
// K_A: one wave per (channel, x-tile, y-strip). Vertical sliding sums of
// I, p, I*p, I*I in registers; per-row chained DPP scan; writes a,b fp16x2.
// ---------------------------------------------------------------------------
__global__ __launch_bounds__(64, 3)
void fused_ab_kernel(const float* __restrict__ I, const float* __restrict__ p,
                     unsigned int* __restrict__ ab) {
    __shared__ __align__(16) float PF[4][512];
    const int l = threadIdx.x;
    const int bid = blockIdx.x;               // natural dispatch order
    const int strip = bid & (NSTRIP - 1);
    const int xt = (bid >> 5) & 3;
    const int c = bid >> 7;
    const int x0 = xt * TX;
    const int y0 = strip * SEGF;
    const size_t plane = (size_t)c * (HH * WW);

    const int g1 = x0 - RAD + 4 * l;     // chunk0 col (mult of 4)
    const int g2 = g1 + 256;             // chunk1 col
    const bool v1 = (g1 >= 0) && (g1 < WW);
    const bool v2 = (l < 20) && (g2 >= 0) && (g2 < WW);

    // vertical sliding sums [field][chunk][k]: 0=I 1=p 2=Ip 3=II
    float s[4][2][4];
    #pragma unroll
    for (int f = 0; f < 4; ++f)
        #pragma unroll
        for (int ch = 0; ch < 2; ++ch)
            #pragma unroll
            for (int k = 0; k < 4; ++k) s[f][ch][k] = 0.f;

    auto load2 = [&](const float* src, int y, float* r) {
        const float* row = src + plane + (size_t)y * WW;
        float4 A = v1 ? *(const float4*)(row + g1) : make_float4(0.f,0.f,0.f,0.f);
        float4 B = v2 ? *(const float4*)(row + g2) : make_float4(0.f,0.f,0.f,0.f);
        r[0]=A.x; r[1]=A.y; r[2]=A.z; r[3]=A.w;
        r[4]=B.x; r[5]=B.y; r[6]=B.z; r[7]=B.w;
    };
    auto acc = [&](const float* ri, const float* rp, float sg) {
        #pragma unroll
        for (int j = 0; j < 8; ++j) {
            const int ch = j >> 2, k = j & 3;
            s[0][ch][k] += sg * ri[j];
            s[1][ch][k] += sg * rp[j];
            s[2][ch][k] += sg * ri[j] * rp[j];
            s[3][ch][k] += sg * ri[j] * ri[j];
        }
    };

    // prime rows [y0-RAD, y0+RAD)
    int yp0 = y0 - RAD; if (yp0 < 0) yp0 = 0;
    int yp1 = y0 + RAD; if (yp1 > HH) yp1 = HH;
    for (int y = yp0; y < yp1; ++y) {
        float ri[8], rp[8];
        load2(I, y, ri); load2(p, y, rp);
        acc(ri, rp, 1.f);
    }

    float pi[8], pp[8];
    if (y0 + RAD < HH) { load2(I, y0 + RAD, pi); load2(p, y0 + RAD, pp); }

    for (int y = y0; y < y0 + SEGF; ++y) {
        if (y + RAD < HH) acc(pi, pp, 1.f);
        // prefetch next add-row and this row's sub-row
        float ni[8], np[8], si[8], sp[8];
        const int yn = y + 1 + RAD;
        const bool nh = (yn < HH) && (y + 1 < y0 + SEGF);
        if (nh) { load2(I, yn, ni); load2(p, yn, np); }
        const int ys = y - RAD;
        if (ys >= 0) { load2(I, ys, si); load2(p, ys, sp); }

        // chained scans (chunk0 then chunk1), prefix -> LDS
        float incl0[4][4];
        #pragma unroll
        for (int f = 0; f < 4; ++f) {
            float c0 = s[f][0][0];
            float c1 = c0 + s[f][0][1];
            float c2 = c1 + s[f][0][2];
            float c3 = c2 + s[f][0][3];
            float t = wscan64(c3);
            float tot0 = __shfl(t, 63);
            float b0 = t - c3;
            float d0 = s[f][1][0];
            float d1 = d0 + s[f][1][1];
            float d2 = d1 + s[f][1][2];
            float d3 = d2 + s[f][1][3];
            float u = wscan64(d3);
            float b1 = tot0 + (u - d3);
            incl0[f][0] = b0 + c0; incl0[f][1] = b0 + c1;
            incl0[f][2] = b0 + c2; incl0[f][3] = b0 + c3;
            ((float4*)PF[f])[l]      = make_float4(incl0[f][0], incl0[f][1], incl0[f][2], incl0[f][3]);
            ((float4*)PF[f])[64 + l] = make_float4(b1 + d0, b1 + d1, b1 + d2, b1 + d3);
        }
        __syncthreads();   // single-wave workgroup: compiler fence, ~free

        int cv_hi = y + RAD + 1; if (cv_hi > HH) cv_hi = HH;
        int cv_lo = y - RAD;     if (cv_lo < 0)  cv_lo = 0;
        const float cntV = (float)(cv_hi - cv_lo);

        float4 hi0 = ((const float4*)PF[0])[l + 20];
        float4 hi1 = ((const float4*)PF[1])[l + 20];
        float4 hi2 = ((const float4*)PF[2])[l + 20];
        float4 hi3 = ((const float4*)PF[3])[l + 20];
        const float* h0 = (const float*)&hi0;
        const float* h1 = (const float*)&hi1;
        const float* h2 = (const float*)&hi2;
        const float* h3 = (const float*)&hi3;

        unsigned int outw[4];
        #pragma unroll
        for (int k = 0; k < 4; ++k) {
            const int go = x0 + 4 * l + k;
            float bI  = h0[k] - (incl0[0][k] - s[0][0][k]);
            float bp  = h1[k] - (incl0[1][k] - s[1][0][k]);
            float bIp = h2[k] - (incl0[2][k] - s[2][0][k]);
            float bII = h3[k] - (incl0[3][k] - s[3][0][k]);
            int hlo = go - RAD;     if (hlo < 0)  hlo = 0;
            int hhi = go + RAD + 1; if (hhi > WW) hhi = WW;
            const float ic = 1.f / (cntV * (float)(hhi - hlo));
            float mI = bI*ic, mp = bp*ic, mIp = bIp*ic, mII = bII*ic;
            float cov = mIp - mI * mp;
            float var = mII - mI * mI;
            float aa = cov / (var + 1e-3f);
            float bb = mp - aa * mI;
            __half2 h = __float22half2_rn(make_float2(aa, bb));
            outw[k] = *reinterpret_cast<unsigned int*>(&h);
        }
        ((uint4*)(ab + plane + (size_t)y * WW))[(x0 >> 2) + l] =
            make_uint4(outw[0], outw[1], outw[2], outw[3]);

        if (ys >= 0) acc(si, sp, -1.f);
        if (nh) {
            #pragma unroll
            for (int j = 0; j < 8; ++j) { pi[j] = ni[j]; pp[j] = np[j]; }
        }
        __syncthreads();   // protect next iter's PF writes vs this iter's reads
    }
}

// ---------------------------------------------------------------------------
// K_B: same structure on packed a,b; epilogue out = mean_a * I + mean_b
// ---------------------------------------------------------------------------
__global__ __launch_bounds__(64, 3)
void fused_out_kernel(const unsigned int* __restrict__ ab, const float* __restrict__ I,
                      float* __restrict__ out) {
    __shared__ __align__(16) float PF[2][512];
    const int l = threadIdx.x;
    const int bid = blockIdx.x;
    const int strip = bid & (NSTRIP - 1);
    const int xt = (bid >> 5) & 3;
    const int c = bid >> 7;
    const int x0 = xt * TX;
    const int y0 = strip * SEGF;
    const size_t plane = (size_t)c * (HH * WW);

    const int g1 = x0 - RAD + 4 * l;
    const int g2 = g1 + 256;
    const bool v1 = (g1 >= 0) && (g1 < WW);
    const bool v2 = (l < 20) && (g2 >= 0) && (g2 < WW);

    float s[2][2][4];
    #pragma unroll
    for (int f = 0; f < 2; ++f)
        #pragma unroll
        for (int ch = 0; ch < 2; ++ch)
            #pragma unroll
            for (int k = 0; k < 4; ++k) s[f][ch][k] = 0.f;

    auto load2u = [&](int y, float* ra, float* rb) {
        const unsigned int* row = ab + plane + (size_t)y * WW;
        uint4 A = v1 ? *(const uint4*)(row + g1) : make_uint4(0u,0u,0u,0u);
        uint4 B = v2 ? *(const uint4*)(row + g2) : make_uint4(0u,0u,0u,0u);
        const unsigned int* aw = (const unsigned int*)&A;
        const unsigned int* bw = (const unsigned int*)&B;
        #pragma unroll
        for (int k = 0; k < 4; ++k) {
            __half2 ha = *reinterpret_cast<const __half2*>(&aw[k]);
            float2 fa = __half22float2(ha);
            ra[k] = fa.x; rb[k] = fa.y;
            __half2 hb = *reinterpret_cast<const __half2*>(&bw[k]);
            float2 fb = __half22float2(hb);
            ra[4+k] = fb.x; rb[4+k] = fb.y;
        }
    };
    auto acc = [&](const float* ra, const float* rb, float sg) {
        #pragma unroll
        for (int j = 0; j < 8; ++j) {
            const int ch = j >> 2, k = j & 3;
            s[0][ch][k] += sg * ra[j];
            s[1][ch][k] += sg * rb[j];
        }
    };

    int yp0 = y0 - RAD; if (yp0 < 0) yp0 = 0;
    int yp1 = y0 + RAD; if (yp1 > HH) yp1 = HH;
    for (int y = yp0; y < yp1; ++y) {
        float ra[8], rb[8];
        load2u(y, ra, rb);
        acc(ra, rb, 1.f);
    }

    float pa[8], pb[8];
    if (y0 + RAD < HH) load2u(y0 + RAD, pa, pb);

    for (int y = y0; y < y0 + SEGF; ++y) {
        if (y + RAD < HH) acc(pa, pb, 1.f);
        float na[8], nb[8], sa[8], sb[8];
        const int yn = y + 1 + RAD;
        const bool nh = (yn < HH) && (y + 1 < y0 + SEGF);
        if (nh) load2u(yn, na, nb);
        const int ys = y - RAD;
        if (ys >= 0) load2u(ys, sa, sb);

        float incl0[2][4];
        #pragma unroll
        for (int f = 0; f < 2; ++f) {
            float c0 = s[f][0][0];
            float c1 = c0 + s[f][0][1];
            float c2 = c1 + s[f][0][2];
            float c3 = c2 + s[f][0][3];
            float t = wscan64(c3);
            float tot0 = __shfl(t, 63);
            float b0 = t - c3;
            float d0 = s[f][1][0];
            float d1 = d0 + s[f][1][1];
            float d2 = d1 + s[f][1][2];
            float d3 = d2 + s[f][1][3];
            float u = wscan64(d3);
            float b1 = tot0 + (u - d3);
            incl0[f][0] = b0 + c0; incl0[f][1] = b0 + c1;
            incl0[f][2] = b0 + c2; incl0[f][3] = b0 + c3;
            ((float4*)PF[f])[l]      = make_float4(incl0[f][0], incl0[f][1], incl0[f][2], incl0[f][3]);
            ((float4*)PF[f])[64 + l] = make_float4(b1 + d0, b1 + d1, b1 + d2, b1 + d3);
        }
        __syncthreads();

        int cv_hi = y + RAD + 1; if (cv_hi > HH) cv_hi = HH;
        int cv_lo = y - RAD;     if (cv_lo < 0)  cv_lo = 0;
        const float cntV = (float)(cv_hi - cv_lo);

        float4 hiA = ((const float4*)PF[0])[l + 20];
        float4 hiB = ((const float4*)PF[1])[l + 20];
        const float* hA = (const float*)&hiA;
        const float* hB = (const float*)&hiB;
        float4 Iv = ((const float4*)(I + plane + (size_t)y * WW))[(x0 >> 2) + l];
        const float* Ik = (const float*)&Iv;

        float oo[4];
        #pragma unroll
        for (int k = 0; k < 4; ++k) {
            const int go = x0 + 4 * l + k;
            float ba = hA[k] - (incl0[0][k] - s[0][0][k]);
            float bb = hB[k] - (incl0[1][k] - s[1][0][k]);
            int hlo = go - RAD;     if (hlo < 0)  hlo = 0;
            int hhi = go + RAD + 1; if (hhi > WW) hhi = WW;
            const float ic = 1.f / (cntV * (float)(hhi - hlo));
            oo[k] = (ba * ic) * Ik[k] + bb * ic;
        }
        ((float4*)(out + plane + (size_t)y * WW))[(x0 >> 2) + l] =
            make_float4(oo[0], oo[1], oo[2], oo[3]);

        if (ys >= 0) acc(sa, sb, -1.f);
        if (nh) {
            #pragma unroll
            for (int j = 0; j < 8; ++j) { pa[j] = na[j]; pb[j] = nb[j]; }
        }
        __syncthreads();
    }
}

extern "C" void kernel_launch(void* const* d_in, const int* in_sizes, int n_in,
                              void* d_out, int out_size, void* d_ws, size_t ws_size,
                              hipStream_t stream) {
    const float* I = (const float*)d_in[0];
    const float* p = (const float*)d_in[1];
    float* out = (float*)d_out;

    const int N = in_sizes[0];           // B*C*H*W
    const int BC = N / (HH * WW);

    unsigned int* ab = (unsigned int*)d_ws;   // fp16x2 {a,b} per pixel

    const int nblk = BC * (WW / TX) * NSTRIP;   // BC * 4 * 32 = 1536
    fused_ab_kernel<<<dim3(nblk), 64, 0, stream>>>(I, p, ab);
    fused_out_kernel<<<dim3(nblk), 64, 0, stream>>>(ab, I, out);
}

// Round 9
// 289.603 us; speedup vs baseline: 1.0868x; 1.0598x over previous
//
#include <hip/hip_runtime.h>
#include <hip/hip_fp16.h>

#define RAD 40
#define SEGF 16          // output rows per wave-strip
#define TX 256           // output cols per tile
#define HH 1024
#define WW 1024
// Round-6 champion (TX=256, SEGF=16, DPP scan, (64,3)) + round-9 changes:
//  (1) __syncthreads -> wave-local fence. Single-wave workgroups: barrier is
//      semantically unneeded (DS ops from one wave complete in order); hipcc
//      lowers s_barrier with a full s_waitcnt vmcnt(0) drain, which forced the
//      8 per-row prefetch loads (~900cyc HBM) to complete BEFORE the epilogue
//      each row. Fence keeps ordering, drops the drain.
//  (2) __shfl(t,63) -> v_readlane: removes a ds_bpermute (~40cyc DS roundtrip)
//      from the serial scan chain (4/row K_A, 2/row K_B).
// History (proven): launch_bounds min-waves>=4 => VGPR=40 + 0.5GB spills
// (r1-4); (.,3) => VGPR>=64, WRITE=48MB (r5,r7). DPP scan beats shfl scan
// (r6: K_A 147->133). TX=128 +13% lane-idle (r7). SEGF=32 cuts fetch 36% but
// time flat -> latency-bound, not traffic-bound (r8). Field-split (r5) and
// XCD remap (r1) regress. Natural block order.

template<int CTRL, int RMASK>
__device__ __forceinline__ float dpp_add(float v) {
    int t = __builtin_amdgcn_update_dpp(0, __float_as_int(v), CTRL, RMASK, 0xf, false);
    return v + __int_as_float(t);
}

__device__ __forceinline__ float wscan64(float v) {
    v = dpp_add<0x111, 0xf>(v);   // row_shr:1  — intra-16 scan
    v = dpp_add<0x112, 0xf>(v);   // row_shr:2
    v = dpp_add<0x114, 0xf>(v);   // row_shr:4
    v = dpp_add<0x118, 0xf>(v);   // row_shr:8
    v = dpp_add<0x142, 0xa>(v);   // row_bcast:15 -> rows 1,3
    v = dpp_add<0x143, 0xc>(v);   // row_bcast:31 -> rows 2,3
    return v;
}

__device__ __forceinline__ float bcast63(float v) {
    return __int_as_float(__builtin_amdgcn_readlane(__float_as_int(v), 63));
}

// Wave-local fence: orders LDS write->read within the single wave (DS pipe is
// in-order per wave) without the s_barrier + vmcnt(0) drain of __syncthreads.
__device__ __forceinline__ void wave_fence() {
    asm volatile("" ::: "memory");
    __builtin_amdgcn_wave_barrier();
}

// ---------------------------------------------------------------------------
// K_A: one wave per (channel, x-tile, y-strip). Vertical sliding sums of
// I, p, I*p, I*I in registers; per-row chained DPP scan; writes a,b fp16x2.
// ---------------------------------------------------------------------------
__global__ __launch_bounds__(64, 3)
void fused_ab_kernel(const float* __restrict__ I, const float* __restrict__ p,
                     unsigned int* __restrict__ ab) {
    __shared__ __align__(16) float PF[4][512];
    const int l = threadIdx.x;
    const int bid = blockIdx.x;               // natural dispatch order
    const int strip = bid & 63;
    const int xt = (bid >> 6) & 3;
    const int c = bid >> 8;
    const int x0 = xt * TX;
    const int y0 = strip * SEGF;
    const size_t plane = (size_t)c * (HH * WW);

    const int g1 = x0 - RAD + 4 * l;     // chunk0 col (mult of 4)
    const int g2 = g1 + 256;             // chunk1 col
    const bool v1 = (g1 >= 0) && (g1 < WW);
    const bool v2 = (l < 20) && (g2 >= 0) && (g2 < WW);

    // vertical sliding sums [field][chunk][k]: 0=I 1=p 2=Ip 3=II
    float s[4][2][4];
    #pragma unroll
    for (int f = 0; f < 4; ++f)
        #pragma unroll
        for (int ch = 0; ch < 2; ++ch)
            #pragma unroll
            for (int k = 0; k < 4; ++k) s[f][ch][k] = 0.f;

    auto load2 = [&](const float* src, int y, float* r) {
        const float* row = src + plane + (size_t)y * WW;
        float4 A = v1 ? *(const float4*)(row + g1) : make_float4(0.f,0.f,0.f,0.f);
        float4 B = v2 ? *(const float4*)(row + g2) : make_float4(0.f,0.f,0.f,0.f);
        r[0]=A.x; r[1]=A.y; r[2]=A.z; r[3]=A.w;
        r[4]=B.x; r[5]=B.y; r[6]=B.z; r[7]=B.w;
    };
    auto acc = [&](const float* ri, const float* rp, float sg) {
        #pragma unroll
        for (int j = 0; j < 8; ++j) {
            const int ch = j >> 2, k = j & 3;
            s[0][ch][k] += sg * ri[j];
            s[1][ch][k] += sg * rp[j];
            s[2][ch][k] += sg * ri[j] * rp[j];
            s[3][ch][k] += sg * ri[j] * ri[j];
        }
    };

    // prime rows [y0-RAD, y0+RAD)
    int yp0 = y0 - RAD; if (yp0 < 0) yp0 = 0;
    int yp1 = y0 + RAD; if (yp1 > HH) yp1 = HH;
    for (int y = yp0; y < yp1; ++y) {
        float ri[8], rp[8];
        load2(I, y, ri); load2(p, y, rp);
        acc(ri, rp, 1.f);
    }

    float pi[8], pp[8];
    if (y0 + RAD < HH) { load2(I, y0 + RAD, pi); load2(p, y0 + RAD, pp); }

    for (int y = y0; y < y0 + SEGF; ++y) {
        if (y + RAD < HH) acc(pi, pp, 1.f);
        // prefetch next add-row and this row's sub-row (now free to stay in
        // flight across the whole iteration — no barrier drain)
        float ni[8], np[8], si[8], sp[8];
        const int yn = y + 1 + RAD;
        const bool nh = (yn < HH) && (y + 1 < y0 + SEGF);
        if (nh) { load2(I, yn, ni); load2(p, yn, np); }
        const int ys = y - RAD;
        if (ys >= 0) { load2(I, ys, si); load2(p, ys, sp); }

        // chained scans (chunk0 then chunk1), prefix -> LDS
        float incl0[4][4];
        #pragma unroll
        for (int f = 0; f < 4; ++f) {
            float c0 = s[f][0][0];
            float c1 = c0 + s[f][0][1];
            float c2 = c1 + s[f][0][2];
            float c3 = c2 + s[f][0][3];
            float t = wscan64(c3);
            float tot0 = bcast63(t);
            float b0 = t - c3;
            float d0 = s[f][1][0];
            float d1 = d0 + s[f][1][1];
            float d2 = d1 + s[f][1][2];
            float d3 = d2 + s[f][1][3];
            float u = wscan64(d3);
            float b1 = tot0 + (u - d3);
            incl0[f][0] = b0 + c0; incl0[f][1] = b0 + c1;
            incl0[f][2] = b0 + c2; incl0[f][3] = b0 + c3;
            ((float4*)PF[f])[l]      = make_float4(incl0[f][0], incl0[f][1], incl0[f][2], incl0[f][3]);
            ((float4*)PF[f])[64 + l] = make_float4(b1 + d0, b1 + d1, b1 + d2, b1 + d3);
        }
        wave_fence();   // single-wave workgroup: ordering only, no drain

        int cv_hi = y + RAD + 1; if (cv_hi > HH) cv_hi = HH;
        int cv_lo = y - RAD;     if (cv_lo < 0)  cv_lo = 0;
        const float cntV = (float)(cv_hi - cv_lo);

        float4 hi0 = ((const float4*)PF[0])[l + 20];
        float4 hi1 = ((const float4*)PF[1])[l + 20];
        float4 hi2 = ((const float4*)PF[2])[l + 20];
        float4 hi3 = ((const float4*)PF[3])[l + 20];
        const float* h0 = (const float*)&hi0;
        const float* h1 = (const float*)&hi1;
        const float* h2 = (const float*)&hi2;
        const float* h3 = (const float*)&hi3;

        unsigned int outw[4];
        #pragma unroll
        for (int k = 0; k < 4; ++k) {
            const int go = x0 + 4 * l + k;
            float bI  = h0[k] - (incl0[0][k] - s[0][0][k]);
            float bp  = h1[k] - (incl0[1][k] - s[1][0][k]);
            float bIp = h2[k] - (incl0[2][k] - s[2][0][k]);
            float bII = h3[k] - (incl0[3][k] - s[3][0][k]);
            int hlo = go - RAD;     if (hlo < 0)  hlo = 0;
            int hhi = go + RAD + 1; if (hhi > WW) hhi = WW;
            const float ic = 1.f / (cntV * (float)(hhi - hlo));
            float mI = bI*ic, mp = bp*ic, mIp = bIp*ic, mII = bII*ic;
            float cov = mIp - mI * mp;
            float var = mII - mI * mI;
            float aa = cov / (var + 1e-3f);
            float bb = mp - aa * mI;
            __half2 h = __float22half2_rn(make_float2(aa, bb));
            outw[k] = *reinterpret_cast<unsigned int*>(&h);
        }
        ((uint4*)(ab + plane + (size_t)y * WW))[(x0 >> 2) + l] =
            make_uint4(outw[0], outw[1], outw[2], outw[3]);

        if (ys >= 0) acc(si, sp, -1.f);
        if (nh) {
            #pragma unroll
            for (int j = 0; j < 8; ++j) { pi[j] = ni[j]; pp[j] = np[j]; }
        }
        wave_fence();   // order next iter's PF writes after this iter's reads
    }
}

// ---------------------------------------------------------------------------
// K_B: same structure on packed a,b; epilogue out = mean_a * I + mean_b
// ---------------------------------------------------------------------------
__global__ __launch_bounds__(64, 3)
void fused_out_kernel(const unsigned int* __restrict__ ab, const float* __restrict__ I,
                      float* __restrict__ out) {
    __shared__ __align__(16) float PF[2][512];
    const int l = threadIdx.x;
    const int bid = blockIdx.x;
    const int strip = bid & 63;
    const int xt = (bid >> 6) & 3;
    const int c = bid >> 8;
    const int x0 = xt * TX;
    const int y0 = strip * SEGF;
    const size_t plane = (size_t)c * (HH * WW);

    const int g1 = x0 - RAD + 4 * l;
    const int g2 = g1 + 256;
    const bool v1 = (g1 >= 0) && (g1 < WW);
    const bool v2 = (l < 20) && (g2 >= 0) && (g2 < WW);

    float s[2][2][4];
    #pragma unroll
    for (int f = 0; f < 2; ++f)
        #pragma unroll
        for (int ch = 0; ch < 2; ++ch)
            #pragma unroll
            for (int k = 0; k < 4; ++k) s[f][ch][k] = 0.f;

    auto load2u = [&](int y, float* ra, float* rb) {
        const unsigned int* row = ab + plane + (size_t)y * WW;
        uint4 A = v1 ? *(const uint4*)(row + g1) : make_uint4(0u,0u,0u,0u);
        uint4 B = v2 ? *(const uint4*)(row + g2) : make_uint4(0u,0u,0u,0u);
        const unsigned int* aw = (const unsigned int*)&A;
        const unsigned int* bw = (const unsigned int*)&B;
        #pragma unroll
        for (int k = 0; k < 4; ++k) {
            __half2 ha = *reinterpret_cast<const __half2*>(&aw[k]);
            float2 fa = __half22float2(ha);
            ra[k] = fa.x; rb[k] = fa.y;
            __half2 hb = *reinterpret_cast<const __half2*>(&bw[k]);
            float2 fb = __half22float2(hb);
            ra[4+k] = fb.x; rb[4+k] = fb.y;
        }
    };
    auto acc = [&](const float* ra, const float* rb, float sg) {
        #pragma unroll
        for (int j = 0; j < 8; ++j) {
            const int ch = j >> 2, k = j & 3;
            s[0][ch][k] += sg * ra[j];
            s[1][ch][k] += sg * rb[j];
        }
    };

    int yp0 = y0 - RAD; if (yp0 < 0) yp0 = 0;
    int yp1 = y0 + RAD; if (yp1 > HH) yp1 = HH;
    for (int y = yp0; y < yp1; ++y) {
        float ra[8], rb[8];
        load2u(y, ra, rb);
        acc(ra, rb, 1.f);
    }

    float pa[8], pb[8];
    if (y0 + RAD < HH) load2u(y0 + RAD, pa, pb);

    for (int y = y0; y < y0 + SEGF; ++y) {
        if (y + RAD < HH) acc(pa, pb, 1.f);
        float na[8], nb[8], sa[8], sb[8];
        const int yn = y + 1 + RAD;
        const bool nh = (yn < HH) && (y + 1 < y0 + SEGF);
        if (nh) load2u(yn, na, nb);
        const int ys = y - RAD;
        if (ys >= 0) load2u(ys, sa, sb);

        float incl0[2][4];
        #pragma unroll
        for (int f = 0; f < 2; ++f) {
            float c0 = s[f][0][0];
            float c1 = c0 + s[f][0][1];
            float c2 = c1 + s[f][0][2];
            float c3 = c2 + s[f][0][3];
            float t = wscan64(c3);
            float tot0 = bcast63(t);
            float b0 = t - c3;
            float d0 = s[f][1][0];
            float d1 = d0 + s[f][1][1];
            float d2 = d1 + s[f][1][2];
            float d3 = d2 + s[f][1][3];
            float u = wscan64(d3);
            float b1 = tot0 + (u - d3);
            incl0[f][0] = b0 + c0; incl0[f][1] = b0 + c1;
            incl0[f][2] = b0 + c2; incl0[f][3] = b0 + c3;
            ((float4*)PF[f])[l]      = make_float4(incl0[f][0], incl0[f][1], incl0[f][2], incl0[f][3]);
            ((float4*)PF[f])[64 + l] = make_float4(b1 + d0, b1 + d1, b1 + d2, b1 + d3);
        }
        wave_fence();

        int cv_hi = y + RAD + 1; if (cv_hi > HH) cv_hi = HH;
        int cv_lo = y - RAD;     if (cv_lo < 0)  cv_lo = 0;
        const float cntV = (float)(cv_hi - cv_lo);

        float4 hiA = ((const float4*)PF[0])[l + 20];
        float4 hiB = ((const float4*)PF[1])[l + 20];
        const float* hA = (const float*)&hiA;
        const float* hB = (const float*)&hiB;
        float4 Iv = ((const float4*)(I + plane + (size_t)y * WW))[(x0 >> 2) + l];
        const float* Ik = (const float*)&Iv;

        float oo[4];
        #pragma unroll
        for (int k = 0; k < 4; ++k) {
            const int go = x0 + 4 * l + k;
            float ba = hA[k] - (incl0[0][k] - s[0][0][k]);
            float bb = hB[k] - (incl0[1][k] - s[1][0][k]);
            int hlo = go - RAD;     if (hlo < 0)  hlo = 0;
            int hhi = go + RAD + 1; if (hhi > WW) hhi = WW;
            const float ic = 1.f / (cntV * (float)(hhi - hlo));
            oo[k] = (ba * ic) * Ik[k] + bb * ic;
        }
        ((float4*)(out + plane + (size_t)y * WW))[(x0 >> 2) + l] =
            make_float4(oo[0], oo[1], oo[2], oo[3]);

        if (ys >= 0) acc(sa, sb, -1.f);
        if (nh) {
            #pragma unroll
            for (int j = 0; j < 8; ++j) { pa[j] = na[j]; pb[j] = nb[j]; }
        }
        wave_fence();
    }
}

extern "C" void kernel_launch(void* const* d_in, const int* in_sizes, int n_in,
                              void* d_out, int out_size, void* d_ws, size_t ws_size,
                              hipStream_t stream) {
    const float* I = (const float*)d_in[0];
    const float* p = (const float*)d_in[1];
    float* out = (float*)d_out;

    const int N = in_sizes[0];           // B*C*H*W
    const int BC = N / (HH * WW);

    unsigned int* ab = (unsigned int*)d_ws;   // fp16x2 {a,b} per pixel

    const int nblk = BC * (WW / TX) * (HH / SEGF);   // BC * 4 * 64
    fused_ab_kernel<<<dim3(nblk), 64, 0, stream>>>(I, p, ab);
    fused_out_kernel<<<dim3(nblk), 64, 0, stream>>>(ab, I, out);
}